// Round 1
// baseline (315.426 us; speedup 1.0000x reference)
//
#include <hip/hip_runtime.h>
#include <cstdint>

#define L_ 4096
#define NC_ 512
#define CD_ 256
#define H_ 8
#define D_ 128
#define B_ 4

// Kernel A: Kt[h][d][n] = sum_c codes[n][c] * Wk[c][h][d]   (transposed for main-kernel coalescing)
//           V [h][n][d] = sum_c codes[n][c] * Wv[c][h][d]
__global__ __launch_bounds__(256) void kv_precompute(
    const float* __restrict__ codes, const float* __restrict__ Wk,
    const float* __restrict__ Wv, float* __restrict__ Kt, float* __restrict__ V)
{
    __shared__ float codes_lds[64][CD_];   // 64 KB
    const int h  = blockIdx.x;
    const int n0 = blockIdx.y * 64;
    const int t  = threadIdx.x;
    {
        const float4* src = (const float4*)(codes + (size_t)n0 * CD_);
        float4* dst = (float4*)&codes_lds[0][0];
        #pragma unroll
        for (int i = 0; i < 16; ++i) dst[t + i*256] = src[t + i*256];
    }
    __syncthreads();
    const int d  = t & 127;
    const int ng = t >> 7;      // 0..1 -> 32 codes each
    float ak[32], av[32];
    #pragma unroll
    for (int j = 0; j < 32; ++j) { ak[j] = 0.f; av[j] = 0.f; }
    for (int c = 0; c < CD_; c += 4) {
        float wk[4], wv[4];
        #pragma unroll
        for (int u = 0; u < 4; ++u) {
            wk[u] = Wk[((size_t)(c+u)*H_ + h)*D_ + d];
            wv[u] = Wv[((size_t)(c+u)*H_ + h)*D_ + d];
        }
        #pragma unroll
        for (int j = 0; j < 32; ++j) {
            float4 cv = *(const float4*)&codes_lds[ng*32 + j][c];  // wave-uniform -> broadcast
            ak[j] = fmaf(cv.x, wk[0], ak[j]); ak[j] = fmaf(cv.y, wk[1], ak[j]);
            ak[j] = fmaf(cv.z, wk[2], ak[j]); ak[j] = fmaf(cv.w, wk[3], ak[j]);
            av[j] = fmaf(cv.x, wv[0], av[j]); av[j] = fmaf(cv.y, wv[1], av[j]);
            av[j] = fmaf(cv.z, wv[2], av[j]); av[j] = fmaf(cv.w, wv[3], av[j]);
        }
    }
    #pragma unroll
    for (int j = 0; j < 32; ++j) {
        int n = n0 + ng*32 + j;
        Kt[((size_t)h*D_ + d)*NC_ + n] = ak[j];
        V [((size_t)h*NC_ + n)*D_ + d] = av[j];
    }
}

// Kernel B: per block = (b, h, 64 l's). q tile in LDS (scaled), loop 8 n-tiles of 64,
// 4x4 register-blocked fp32 FMA, top-1 tracked per thread, shfl-reduced over 16-lane
// n-groups, then fused gather of V[idx] into out (coalesced along l).
__global__ __launch_bounds__(256) void hard_attn_main(
    const float* __restrict__ x, const float* __restrict__ Kt,
    const float* __restrict__ V, float* __restrict__ out, float* __restrict__ idxf)
{
    __shared__ float q_lds[D_][64];   // 32 KB
    __shared__ float k_lds[D_][64];   // 32 KB  (total 64 KB exactly)
    const int t  = threadIdx.x;
    const int l0 = blockIdx.x * 64;
    const int h  = blockIdx.y;
    const int b  = blockIdx.z;
    const float scale = 0.08838834764831845f;  // 128^-0.5, matches ref's q = scale*x rounding

    // stage q tile: q_lds[d][l] = scale * x[b][h*128+d][l0+l]
    {
        float4* dst = (float4*)&q_lds[0][0];
        #pragma unroll
        for (int i = 0; i < 8; ++i) {
            int f = t + i*256;
            int row = f >> 4, c4 = f & 15;
            float4 v = *(const float4*)(x + ((size_t)b*1024 + h*D_ + row)*L_ + l0 + c4*4);
            v.x *= scale; v.y *= scale; v.z *= scale; v.w *= scale;
            dst[f] = v;
        }
    }

    const int tn = t & 15;   // 16 n-groups of 4
    const int tl = t >> 4;   // 16 l-groups of 4
    float best[4];
    int   bidx[4];
    #pragma unroll
    for (int i = 0; i < 4; ++i) { best[i] = -1e30f; bidx[i] = 0; }

    for (int nt = 0; nt < 8; ++nt) {
        __syncthreads();   // protect k_lds from previous iteration's readers (and q_lds visibility on iter 0)
        {
            float4* dst = (float4*)&k_lds[0][0];
            #pragma unroll
            for (int i = 0; i < 8; ++i) {
                int f = t + i*256;
                int row = f >> 4, c4 = f & 15;
                dst[f] = *(const float4*)(Kt + ((size_t)h*D_ + row)*NC_ + nt*64 + c4*4);
            }
        }
        __syncthreads();

        float acc[4][4];
        #pragma unroll
        for (int i = 0; i < 4; ++i)
            #pragma unroll
            for (int j = 0; j < 4; ++j) acc[i][j] = 0.f;

        #pragma unroll 8
        for (int dd = 0; dd < D_; ++dd) {
            float4 qv = *(const float4*)&q_lds[dd][tl*4];
            float4 kv = *(const float4*)&k_lds[dd][tn*4];
            acc[0][0] = fmaf(qv.x, kv.x, acc[0][0]);
            acc[0][1] = fmaf(qv.x, kv.y, acc[0][1]);
            acc[0][2] = fmaf(qv.x, kv.z, acc[0][2]);
            acc[0][3] = fmaf(qv.x, kv.w, acc[0][3]);
            acc[1][0] = fmaf(qv.y, kv.x, acc[1][0]);
            acc[1][1] = fmaf(qv.y, kv.y, acc[1][1]);
            acc[1][2] = fmaf(qv.y, kv.z, acc[1][2]);
            acc[1][3] = fmaf(qv.y, kv.w, acc[1][3]);
            acc[2][0] = fmaf(qv.z, kv.x, acc[2][0]);
            acc[2][1] = fmaf(qv.z, kv.y, acc[2][1]);
            acc[2][2] = fmaf(qv.z, kv.z, acc[2][2]);
            acc[2][3] = fmaf(qv.z, kv.w, acc[2][3]);
            acc[3][0] = fmaf(qv.w, kv.x, acc[3][0]);
            acc[3][1] = fmaf(qv.w, kv.y, acc[3][1]);
            acc[3][2] = fmaf(qv.w, kv.z, acc[3][2]);
            acc[3][3] = fmaf(qv.w, kv.w, acc[3][3]);
        }

        // update running top-1 (ascending n => strict '>' keeps first max, matching jnp.argmax)
        #pragma unroll
        for (int i = 0; i < 4; ++i)
            #pragma unroll
            for (int j = 0; j < 4; ++j) {
                float v = acc[i][j];
                if (v > best[i]) { best[i] = v; bidx[i] = nt*64 + tn*4 + j; }
            }
    }
    __syncthreads();   // all q_lds readers done; safe to alias it below

    int* sidx = (int*)&q_lds[0][0];
    #pragma unroll
    for (int i = 0; i < 4; ++i) {
        float v = best[i]; int ix = bidx[i];
        #pragma unroll
        for (int m = 1; m < 16; m <<= 1) {
            float ov = __shfl_xor(v, m, 64);
            int   oi = __shfl_xor(ix, m, 64);
            if (ov > v || (ov == v && oi < ix)) { v = ov; ix = oi; }
        }
        if (tn == 0) sidx[tl*4 + i] = ix;
    }
    __syncthreads();

    // fused gather: out[b][h*128+d][l0+l] = V[h][idx_l][d]
    const int l = t & 63, dg = t >> 6;   // 4 d-groups of 32
    const int ix = sidx[l];
    const float4* vrow = (const float4*)(V + ((size_t)h*NC_ + ix)*D_);
    float* obase = out + ((size_t)b*1024 + h*D_ + dg*32)*L_ + (size_t)l0 + l;
    #pragma unroll
    for (int p = 0; p < 8; ++p) {
        float4 vv = vrow[dg*8 + p];
        obase[(size_t)(p*4+0)*L_] = vv.x;
        obase[(size_t)(p*4+1)*L_] = vv.y;
        obase[(size_t)(p*4+2)*L_] = vv.z;
        obase[(size_t)(p*4+3)*L_] = vv.w;
    }
    if (t < 64) idxf[((size_t)b*H_ + h)*L_ + l0 + t] = (float)sidx[t];
}

extern "C" void kernel_launch(void* const* d_in, const int* in_sizes, int n_in,
                              void* d_out, int out_size, void* d_ws, size_t ws_size,
                              hipStream_t stream)
{
    const float* x     = (const float*)d_in[0];
    const float* codes = (const float*)d_in[1];
    const float* Wk    = (const float*)d_in[2];
    const float* Wv    = (const float*)d_in[3];

    float* out  = (float*)d_out;
    float* idxf = out + (size_t)B_ * H_ * D_ * L_;   // idx written as float32 values

    // workspace: Kt (2 MB) + V (2 MB)
    float* Kt = (float*)d_ws;
    float* V  = Kt + (size_t)H_ * D_ * NC_;

    kv_precompute<<<dim3(H_, NC_/64), 256, 0, stream>>>(codes, Wk, Wv, Kt, V);
    hard_attn_main<<<dim3(L_/64, H_, B_), 256, 0, stream>>>(x, Kt, V, out, idxf);
}